// Round 10
// baseline (549.508 us; speedup 1.0000x reference)
//
#include <hip/hip_runtime.h>
#include <stdint.h>

#define N_NODES 100000
#define N_EDGES 3200000
#define IN_DIM  81
#define HID     64
#define LAT     32
#define BN_EPS  1e-5f
#define NBUCKET 391      /* ceil(N_NODES/256) */
#define EPB     2048     /* edges per block in scatter (small -> occupancy) */
#define NBLK_E  1563     /* ceil(N_EDGES/EPB) */
#define BCAP    16384    /* fixed bucket capacity (expected ~8184 +- 90) */

__device__ __forceinline__ float bfu2f(unsigned short u) {
    return __uint_as_float(((uint32_t)u) << 16);
}
__device__ __forceinline__ unsigned short f2bfu(float f) {
    uint32_t x = __float_as_uint(f);
    return (unsigned short)((x + 0x7FFFu + ((x >> 16) & 1u)) >> 16);
}
__device__ __forceinline__ float loadf(const void* p, size_t i, int fp32) {
    if (fp32) return ((const float*)p)[i];
    return bfu2f(((const unsigned short*)p)[i]);
}
__device__ __forceinline__ int load_dst(const void* ei, int f64, long e) {
    if (f64) return (int)(((const long long*)ei)[(size_t)N_EDGES + e]);
    return ((const int*)ei)[(size_t)N_EDGES + e];
}
__device__ __forceinline__ int load_src(const void* ei, int f64, long e) {
    if (f64) return (int)(((const long long*)ei)[e]);
    return ((const int*)ei)[e];
}
// wave-uniform broadcast of lane k's value (k must be compile-time constant)
__device__ __forceinline__ float bcast(float v, int k) {
    return __int_as_float(__builtin_amdgcn_readlane(__float_as_int(v), k));
}

// unpack 8 bf16 (uint4) and fma into acc[8] with scalar weight d
__device__ __forceinline__ void fma8(float* acc, uint4 v, float d) {
    acc[0] = fmaf(__uint_as_float(v.x << 16), d, acc[0]);
    acc[1] = fmaf(__uint_as_float(v.x & 0xffff0000u), d, acc[1]);
    acc[2] = fmaf(__uint_as_float(v.y << 16), d, acc[2]);
    acc[3] = fmaf(__uint_as_float(v.y & 0xffff0000u), d, acc[3]);
    acc[4] = fmaf(__uint_as_float(v.z << 16), d, acc[4]);
    acc[5] = fmaf(__uint_as_float(v.z & 0xffff0000u), d, acc[5]);
    acc[6] = fmaf(__uint_as_float(v.w << 16), d, acc[6]);
    acc[7] = fmaf(__uint_as_float(v.w & 0xffff0000u), d, acc[7]);
}

__global__ void stamp_kernel(float* out, int n, float v) {
    int i = blockIdx.x * blockDim.x + threadIdx.x;
    if (i < n) out[i] = v;
}

// flags[0]: edge int64?  flags[1+b]: per-float-input fp32?
// w=0..12: one wave per buffer; w=13: edge probe + zero gcnt;
// w=14/15: zero statsA/statsB (128 floats each).
__global__ void detect_all(const int* ei_raw,
                           const void* x, const void* W1, const void* b1,
                           const void* g1, const void* be1, const void* W2,
                           const void* b2, const void* g2, const void* be2,
                           const void* Wmu, const void* bmu, const void* Wls,
                           const void* bls, int* flags,
                           float* statsA, float* statsB, int* gcnt) {
    int w = threadIdx.x >> 6;
    int lane = threadIdx.x & 63;
    if (w == 14) {
        for (int i = lane; i < 128; i += 64) statsA[i] = 0.0f;
        return;
    }
    if (w == 15) {
        for (int i = lane; i < 128; i += 64) statsB[i] = 0.0f;
        return;
    }
    if (w == 13) {
        int acc = ei_raw[2 * lane * 11003 + 1] |
                  ei_raw[2 * (lane + 64) * 11003 + 1];
        unsigned long long b = __ballot(acc != 0);
        if (lane == 0) flags[0] = (b == 0ull) ? 1 : 0;
        for (int i = lane; i < NBUCKET; i += 64) gcnt[i] = 0;
        return;
    }
    const void* bufs[13] = { x, W1, b1, g1, be1, W2, b2, g2, be2, Wmu, bmu, Wls, bls };
    const int   ns[13]   = { 512, 512, 64, 64, 64, 512, 64, 64, 64, 512, 32, 512, 32 };
    const unsigned short* u = (const unsigned short*)bufs[w];
    int n = ns[w];
    int evenZero = 0;
    bool oddNz = false, anyNz = false, big = false;
    for (int i = lane; i < n; i += 64) {
        unsigned short s = u[i];
        if (s) anyNz = true;
        if (i & 1) { if (s) oddNz = true; }
        else {
            if ((s & 0x7F80u) == 0x7F80u) big = true;
            else if (fabsf(bfu2f(s)) > 100.0f) big = true;
            if (s == 0) evenZero++;
        }
    }
    unsigned long long anyB = __ballot(anyNz);
    unsigned long long oddB = __ballot(oddNz);
    unsigned long long bigB = __ballot(big);
#pragma unroll
    for (int o = 1; o < 64; o <<= 1) evenZero += __shfl_xor(evenZero, o);
    if (lane == 0) {
        int fp32 = 0;
        if (anyB != 0ull) {
            if (bigB != 0ull) fp32 = 1;
            else if (evenZero >= n / 4 && oddB != 0ull) fp32 = 1;
        }
        flags[1 + w] = fp32;
    }
}

__global__ void convert_weights(const void* W1, const void* W2,
                                const void* Wmu, const void* Wls,
                                const void* b1, const void* b2,
                                const void* bmu, const void* bls,
                                const int* flags,
                                float* W1f, float* W2f, float* Wcatf,
                                float* b1f, float* b2f, float* bcatf) {
    int i = blockIdx.x * blockDim.x + threadIdx.x;
    if (i < IN_DIM * HID) { W1f[i] = loadf(W1, i, flags[2]); return; }
    i -= IN_DIM * HID;
    if (i < HID * HID) { W2f[i] = loadf(W2, i, flags[6]); return; }
    i -= HID * HID;
    if (i < HID * HID) {
        int k = i >> 6;
        int j = i & 63;
        if (j < LAT) Wcatf[i] = loadf(Wmu, (size_t)k * LAT + j, flags[10]);
        else         Wcatf[i] = loadf(Wls, (size_t)k * LAT + (j - LAT), flags[12]);
        return;
    }
    i -= HID * HID;
    if (i < HID) { b1f[i] = loadf(b1, i, flags[3]); return; }
    i -= HID;
    if (i < HID) { b2f[i] = loadf(b2, i, flags[7]); return; }
    i -= HID;
    if (i < HID) {
        if (i < LAT) bcatf[i] = loadf(bmu, i, flags[11]);
        else         bcatf[i] = loadf(bls, i - LAT, flags[13]);
    }
}

// ---- single-pass bucketed scatter (fixed-capacity buckets) ----
__global__ void bucket_scatter(const void* ei, const int* flags, int* gcnt,
                               int* staged) {
    __shared__ int h[NBUCKET];
    __shared__ int lbase[NBUCKET];
    __shared__ int lcnt[NBUCKET];
    for (int i = threadIdx.x; i < NBUCKET; i += 256) { h[i] = 0; lcnt[i] = 0; }
    __syncthreads();
    int f64 = flags[0];
    long e0 = (long)blockIdx.x * EPB;
    for (int i = 0; i < EPB / 256; i++) {
        long e = e0 + i * 256 + threadIdx.x;
        if (e < N_EDGES) atomicAdd(&h[load_dst(ei, f64, e) >> 8], 1);
    }
    __syncthreads();
    for (int i = threadIdx.x; i < NBUCKET; i += 256)
        lbase[i] = h[i] ? atomicAdd(&gcnt[i], h[i]) : 0;
    __syncthreads();
    for (int i = 0; i < EPB / 256; i++) {
        long e = e0 + i * 256 + threadIdx.x;
        if (e < N_EDGES) {
            int d = load_dst(ei, f64, e);
            int s = load_src(ei, f64, e);
            int b = d >> 8;
            int off = atomicAdd(&lcnt[b], 1);
            staged[(b << 14) + lbase[b] + off] = ((d & 255) << 17) | s;
        }
    }
}

// one block (1024 threads) per bucket: prefix over gcnt, deg/scan, scatter.
// Edge loops use all 1024 threads; 256-wide scan phases guard with t<256.
__global__ void csr_build(const int* gcnt, const int* staged, float* dis,
                          int* row_start, int* csr) {
    int b = blockIdx.x;
    int t = threadIdx.x;
    int n0 = b << 8;
    int nn = N_NODES - n0;
    if (nn > 256) nn = 256;
    __shared__ int sd[256];
    __shared__ int ldeg[256];
    __shared__ int lcur[256];
    __shared__ int se0;
    if (t < 256) {
        int p = 0;
        for (int i = t; i < b; i += 256) p += gcnt[i];
        sd[t] = p;
    }
    __syncthreads();
    for (int off = 128; off >= 1; off >>= 1) {
        if (t < off) sd[t] += sd[t + off];
        __syncthreads();
    }
    if (t == 0) se0 = sd[0];
    if (t < 256) ldeg[t] = 0;
    __syncthreads();
    int e0 = se0;
    int cntb = gcnt[b];
    const int* sb = staged + ((size_t)b << 14);
    for (int i = t; i < cntb; i += 1024)
        atomicAdd(&ldeg[sb[i] >> 17], 1);
    __syncthreads();
    int v = 0;
    if (t < 256) { v = ldeg[t]; sd[t] = v; }
    __syncthreads();
    for (int off = 1; off < 256; off <<= 1) {
        int x = 0;
        if (t < 256 && t >= off) x = sd[t - off];
        __syncthreads();
        if (t < 256) sd[t] += x;
        __syncthreads();
    }
    if (t < 256) {
        int excl = sd[t] - v;
        if (t < nn) {
            dis[n0 + t] = rsqrtf((float)(v + 1));
            row_start[n0 + t] = e0 + excl;
        }
        lcur[t] = e0 + excl;
    }
    __syncthreads();
    for (int i = t; i < cntb; i += 1024) {
        int rec = sb[i];
        int pos = atomicAdd(&lcur[rec >> 17], 1);
        csr[pos] = rec & 0x1FFFF;
    }
    if (b == NBUCKET - 1 && t == 0) row_start[N_NODES] = e0 + cntb;
}

// ---- dense layers: one wave per 4 nodes, lane = output feature ----
__global__ void gemm_l1(const void* X, const int* flags, const float* W,
                        unsigned short* T) {
    int wid = (blockIdx.x * blockDim.x + threadIdx.x) >> 6;
    int n0 = wid * 4;
    if (n0 >= N_NODES) return;
    int lane = threadIdx.x & 63;
    int fp = flags[1];
    float xa[4], xb[4];
#pragma unroll
    for (int nn = 0; nn < 4; nn++) {
        size_t base = (size_t)(n0 + nn) * IN_DIM;
        xa[nn] = loadf(X, base + lane, fp);
        xb[nn] = (lane < IN_DIM - 64) ? loadf(X, base + 64 + lane, fp) : 0.0f;
    }
    float acc[4] = { 0.0f, 0.0f, 0.0f, 0.0f };
    const float* Wp = W + lane;
#pragma unroll
    for (int k = 0; k < 64; k++) {
        float w = Wp[k * HID];
#pragma unroll
        for (int nn = 0; nn < 4; nn++)
            acc[nn] = fmaf(bcast(xa[nn], k), w, acc[nn]);
    }
#pragma unroll
    for (int k = 0; k < IN_DIM - 64; k++) {
        float w = Wp[(64 + k) * HID];
#pragma unroll
        for (int nn = 0; nn < 4; nn++)
            acc[nn] = fmaf(bcast(xb[nn], k), w, acc[nn]);
    }
#pragma unroll
    for (int nn = 0; nn < 4; nn++)
        T[(size_t)(n0 + nn) * HID + lane] = f2bfu(acc[nn]);
}

// BN finalize inlined: lane reads stats[lane]/stats[64+lane] (L2-cached),
// computes scale/shift, then gemm.
__global__ void gemm_bn(const float* F, const float* W, const float* stats,
                        const void* gw, const void* bw, const int* flags,
                        int gf, int bf, unsigned short* T) {
    int wid = (blockIdx.x * blockDim.x + threadIdx.x) >> 6;
    int n0 = wid * 4;
    if (n0 >= N_NODES) return;
    int lane = threadIdx.x & 63;
    float s = stats[lane];
    float q = stats[64 + lane];
    const float inv_n = 1.0f / (float)N_NODES;
    float mean = s * inv_n;
    float var = q * inv_n - mean * mean;
    float sc = loadf(gw, lane, flags[gf]) * rsqrtf(var + BN_EPS);
    float sh = loadf(bw, lane, flags[bf]) - mean * sc;
    float a[4];
#pragma unroll
    for (int nn = 0; nn < 4; nn++) {
        float f = F[(size_t)(n0 + nn) * HID + lane];
        a[nn] = fmaxf(f * sc + sh, 0.0f);
    }
    float acc[4] = { 0.0f, 0.0f, 0.0f, 0.0f };
    const float* Wp = W + lane;
#pragma unroll
    for (int k = 0; k < HID; k++) {
        float w = Wp[k * HID];
#pragma unroll
        for (int nn = 0; nn < 4; nn++)
            acc[nn] = fmaf(bcast(a[nn], k), w, acc[nn]);
    }
#pragma unroll
    for (int nn = 0; nn < 4; nn++)
        T[(size_t)(n0 + nn) * HID + lane] = f2bfu(acc[nn]);
}

// ---- aggregation: one wave per node, lane = g*8+c, 4 chains ----
__global__ void agg_mid(const unsigned short* T, const int* row_start, const int* csr,
                        const float* dis, const float* bias, float* F) {
    int wid = (blockIdx.x * blockDim.x + threadIdx.x) >> 6;
    if (wid >= N_NODES) return;
    int lane = threadIdx.x & 63;
    int g = lane >> 3;
    int c = lane & 7;
    float dn = dis[wid];
    float acc[8];
#pragma unroll
    for (int k = 0; k < 8; k++) acc[k] = 0.0f;
    if (g == 0) {
        uint4 v = ((const uint4*)(T + (size_t)wid * HID))[c];
        fma8(acc, v, dn);
    }
    int s0 = row_start[wid];
    int s1 = row_start[wid + 1];
    for (int e = s0; e < s1; e += 32) {
        int i0 = e + g;
        int i1 = e + 8 + g;
        int i2 = e + 16 + g;
        int i3 = e + 24 + g;
        int m0 = i0 < s1, m1 = i1 < s1, m2 = i2 < s1, m3 = i3 < s1;
        int n0i = csr[m0 ? i0 : s0];
        int n1i = csr[m1 ? i1 : s0];
        int n2i = csr[m2 ? i2 : s0];
        int n3i = csr[m3 ? i3 : s0];
        float d0 = m0 ? dis[n0i] : 0.0f;
        float d1 = m1 ? dis[n1i] : 0.0f;
        float d2 = m2 ? dis[n2i] : 0.0f;
        float d3 = m3 ? dis[n3i] : 0.0f;
        uint4 v0 = ((const uint4*)(T + (size_t)n0i * HID))[c];
        uint4 v1 = ((const uint4*)(T + (size_t)n1i * HID))[c];
        uint4 v2 = ((const uint4*)(T + (size_t)n2i * HID))[c];
        uint4 v3 = ((const uint4*)(T + (size_t)n3i * HID))[c];
        fma8(acc, v0, d0);
        fma8(acc, v1, d1);
        fma8(acc, v2, d2);
        fma8(acc, v3, d3);
    }
#pragma unroll
    for (int k = 0; k < 8; k++) {
        float v = acc[k];
        v += __shfl_xor(v, 8);
        v += __shfl_xor(v, 16);
        v += __shfl_xor(v, 32);
        acc[k] = v;
    }
    if (g == 0) {
        const float4* bp = (const float4*)(bias + c * 8);
        float4 b0 = bp[0];
        float4 b1 = bp[1];
        float4 r0, r1;
        r0.x = b0.x + dn * acc[0];
        r0.y = b0.y + dn * acc[1];
        r0.z = b0.z + dn * acc[2];
        r0.w = b0.w + dn * acc[3];
        r1.x = b1.x + dn * acc[4];
        r1.y = b1.y + dn * acc[5];
        r1.z = b1.z + dn * acc[6];
        r1.w = b1.w + dn * acc[7];
        float4* o = (float4*)(F + (size_t)wid * HID + c * 8);
        o[0] = r0;
        o[1] = r1;
    }
}

__global__ void agg_out(const unsigned short* T, const int* row_start, const int* csr,
                        const float* dis, const float* bias, float* out) {
    int wid = (blockIdx.x * blockDim.x + threadIdx.x) >> 6;
    if (wid >= N_NODES) return;
    int lane = threadIdx.x & 63;
    int g = lane >> 3;
    int c = lane & 7;
    float dn = dis[wid];
    float acc[8];
#pragma unroll
    for (int k = 0; k < 8; k++) acc[k] = 0.0f;
    if (g == 0) {
        uint4 v = ((const uint4*)(T + (size_t)wid * HID))[c];
        fma8(acc, v, dn);
    }
    int s0 = row_start[wid];
    int s1 = row_start[wid + 1];
    for (int e = s0; e < s1; e += 32) {
        int i0 = e + g;
        int i1 = e + 8 + g;
        int i2 = e + 16 + g;
        int i3 = e + 24 + g;
        int m0 = i0 < s1, m1 = i1 < s1, m2 = i2 < s1, m3 = i3 < s1;
        int n0i = csr[m0 ? i0 : s0];
        int n1i = csr[m1 ? i1 : s0];
        int n2i = csr[m2 ? i2 : s0];
        int n3i = csr[m3 ? i3 : s0];
        float d0 = m0 ? dis[n0i] : 0.0f;
        float d1 = m1 ? dis[n1i] : 0.0f;
        float d2 = m2 ? dis[n2i] : 0.0f;
        float d3 = m3 ? dis[n3i] : 0.0f;
        uint4 v0 = ((const uint4*)(T + (size_t)n0i * HID))[c];
        uint4 v1 = ((const uint4*)(T + (size_t)n1i * HID))[c];
        uint4 v2 = ((const uint4*)(T + (size_t)n2i * HID))[c];
        uint4 v3 = ((const uint4*)(T + (size_t)n3i * HID))[c];
        fma8(acc, v0, d0);
        fma8(acc, v1, d1);
        fma8(acc, v2, d2);
        fma8(acc, v3, d3);
    }
#pragma unroll
    for (int k = 0; k < 8; k++) {
        float v = acc[k];
        v += __shfl_xor(v, 8);
        v += __shfl_xor(v, 16);
        v += __shfl_xor(v, 32);
        acc[k] = v;
    }
    if (g == 0) {
        const float4* bp = (const float4*)(bias + c * 8);
        float4 b0 = bp[0];
        float4 b1 = bp[1];
        float4 r0, r1;
        r0.x = b0.x + dn * acc[0];
        r0.y = b0.y + dn * acc[1];
        r0.z = b0.z + dn * acc[2];
        r0.w = b0.w + dn * acc[3];
        r1.x = b1.x + dn * acc[4];
        r1.y = b1.y + dn * acc[5];
        r1.z = b1.z + dn * acc[6];
        r1.w = b1.w + dn * acc[7];
        float4* o;
        if (c < 4)
            o = (float4*)(out + (size_t)wid * LAT + c * 8);
        else
            o = (float4*)(out + (size_t)N_NODES * LAT + (size_t)wid * LAT + (c - 4) * 8);
        o[0] = r0;
        o[1] = r1;
    }
}

__global__ void stats_kernel(const float* F, float* stats) {
    int lane = threadIdx.x & 63;
    float s = 0.0f;
    float q = 0.0f;
    int wv = threadIdx.x >> 6;
    for (int r = blockIdx.x * 4 + wv; r < N_NODES; r += gridDim.x * 4) {
        float v = F[(size_t)r * HID + lane];
        s += v;
        q += v * v;
    }
    __shared__ float ls[256];
    __shared__ float lq[256];
    ls[threadIdx.x] = s;
    lq[threadIdx.x] = q;
    __syncthreads();
    if (threadIdx.x < 64) {
        s = ls[threadIdx.x] + ls[64 + threadIdx.x] + ls[128 + threadIdx.x] + ls[192 + threadIdx.x];
        q = lq[threadIdx.x] + lq[64 + threadIdx.x] + lq[128 + threadIdx.x] + lq[192 + threadIdx.x];
        atomicAdd(&stats[lane], s);
        atomicAdd(&stats[64 + lane], q);
    }
}

extern "C" void kernel_launch(void* const* d_in, const int* in_sizes, int n_in,
                              void* d_out, int out_size, void* d_ws, size_t ws_size,
                              hipStream_t stream) {
    (void)in_sizes;
    (void)n_in;
    const void* x   = d_in[0];
    const void* ei  = d_in[1];
    const void* W1  = d_in[2];
    const void* b1  = d_in[3];
    const void* g1  = d_in[4];
    const void* be1 = d_in[5];
    const void* W2  = d_in[6];
    const void* b2  = d_in[7];
    const void* g2  = d_in[8];
    const void* be2 = d_in[9];
    const void* Wmu = d_in[10];
    const void* bmu = d_in[11];
    const void* Wls = d_in[12];
    const void* bls = d_in[13];
    float* out = (float*)d_out;

    char* base = (char*)d_ws;
    size_t off = 0;
    // staged (NBUCKET*BCAP ints) unioned with F (N_NODES*HID floats):
    // staged dead after csr_build; F first written by agg_mid (later).
    int*   staged = (int*)(base + off);
    float* F      = (float*)(base + off);
    size_t uni = (size_t)NBUCKET * BCAP * 4;
    if ((size_t)N_NODES * HID * 4 > uni) uni = (size_t)N_NODES * HID * 4;
    off += uni;                        off = (off + 511) & ~(size_t)511;
    int* csr = (int*)(base + off);
    off += (size_t)N_EDGES * 4;        off = (off + 511) & ~(size_t)511;
    unsigned short* T = (unsigned short*)(base + off);
    off += (size_t)N_NODES * HID * 2;  off = (off + 511) & ~(size_t)511;
    float* dis = (float*)(base + off);
    off += (size_t)N_NODES * 4;        off = (off + 511) & ~(size_t)511;
    int* row_start = (int*)(base + off);
    off += (size_t)(N_NODES + 1) * 4;  off = (off + 511) & ~(size_t)511;
    int* gcnt = (int*)(base + off);
    off += NBUCKET * 4;                off = (off + 511) & ~(size_t)511;
    int* flags = (int*)(base + off);
    off += 512;                        off = (off + 511) & ~(size_t)511;
    float* W1f = (float*)(base + off);
    off += (size_t)IN_DIM * HID * 4;   off = (off + 511) & ~(size_t)511;
    float* W2f = (float*)(base + off);
    off += (size_t)HID * HID * 4;      off = (off + 511) & ~(size_t)511;
    float* Wcatf = (float*)(base + off);
    off += (size_t)HID * HID * 4;      off = (off + 511) & ~(size_t)511;
    float* b1f = (float*)(base + off);
    off += HID * 4;                    off = (off + 511) & ~(size_t)511;
    float* b2f = (float*)(base + off);
    off += HID * 4;                    off = (off + 511) & ~(size_t)511;
    float* bcatf = (float*)(base + off);
    off += HID * 4;                    off = (off + 511) & ~(size_t)511;
    float* statsA = (float*)(base + off);
    off += 128 * 4;                    off = (off + 511) & ~(size_t)511;
    float* statsB = (float*)(base + off);
    off += 128 * 4;                    off = (off + 511) & ~(size_t)511;

    const int BT = 256;
    int gW   = (N_NODES * 64 + BT - 1) / BT;         // 25000 (wave per node)
    int gG   = ((N_NODES / 4) * 64 + BT - 1) / BT;   // 6250  (wave per 4 nodes)
    int gOut = (out_size + BT - 1) / BT;
    int gCv  = (IN_DIM * HID + 2 * HID * HID + 3 * HID + BT - 1) / BT;

    if (ws_size < off) {
        stamp_kernel<<<gOut, BT, 0, stream>>>(out, out_size, 6.8e37f);
        return;
    }

    detect_all<<<1, 1024, 0, stream>>>((const int*)ei, x, W1, b1, g1, be1, W2, b2,
                                       g2, be2, Wmu, bmu, Wls, bls, flags,
                                       statsA, statsB, gcnt);
    convert_weights<<<gCv, BT, 0, stream>>>(W1, W2, Wmu, Wls, b1, b2, bmu, bls,
                                            flags, W1f, W2f, Wcatf, b1f, b2f, bcatf);

    // CSR build: single-pass scatter into fixed-capacity buckets, then build
    bucket_scatter<<<NBLK_E, BT, 0, stream>>>(ei, flags, gcnt, staged);
    csr_build<<<NBUCKET, 1024, 0, stream>>>(gcnt, staged, dis, row_start, csr);

    // layer 1
    gemm_l1<<<gG, BT, 0, stream>>>(x, flags, W1f, T);
    agg_mid<<<gW, BT, 0, stream>>>(T, row_start, csr, dis, b1f, F);
    stats_kernel<<<256, BT, 0, stream>>>(F, statsA);

    // layer 2 (BN1 finalize inlined)
    gemm_bn<<<gG, BT, 0, stream>>>(F, W2f, statsA, g1, be1, flags, 4, 5, T);
    agg_mid<<<gW, BT, 0, stream>>>(T, row_start, csr, dis, b2f, F);
    stats_kernel<<<256, BT, 0, stream>>>(F, statsB);

    // layer 3 (BN2 finalize inlined) -> output
    gemm_bn<<<gG, BT, 0, stream>>>(F, Wcatf, statsB, g2, be2, flags, 8, 9, T);
    agg_out<<<gW, BT, 0, stream>>>(T, row_start, csr, dis, bcatf, out);
}

// Round 11
// 515.468 us; speedup vs baseline: 1.0660x; 1.0660x over previous
//
#include <hip/hip_runtime.h>
#include <stdint.h>

#define N_NODES 100000
#define N_EDGES 3200000
#define IN_DIM  81
#define HID     64
#define LAT     32
#define BN_EPS  1e-5f
#define NBUCKET 391      /* ceil(N_NODES/256) */
#define EPB     8192     /* edges per block in scatter (write-granularity sweet spot) */
#define NBLK_E  391      /* ceil(N_EDGES/EPB) */
#define SCT     1024     /* scatter block size: 16 waves/block for occupancy */
#define BCAP    16384    /* fixed bucket capacity (expected ~8184 +- 90) */

__device__ __forceinline__ float bfu2f(unsigned short u) {
    return __uint_as_float(((uint32_t)u) << 16);
}
__device__ __forceinline__ unsigned short f2bfu(float f) {
    uint32_t x = __float_as_uint(f);
    return (unsigned short)((x + 0x7FFFu + ((x >> 16) & 1u)) >> 16);
}
__device__ __forceinline__ float loadf(const void* p, size_t i, int fp32) {
    if (fp32) return ((const float*)p)[i];
    return bfu2f(((const unsigned short*)p)[i]);
}
__device__ __forceinline__ int load_dst(const void* ei, int f64, long e) {
    if (f64) return (int)(((const long long*)ei)[(size_t)N_EDGES + e]);
    return ((const int*)ei)[(size_t)N_EDGES + e];
}
__device__ __forceinline__ int load_src(const void* ei, int f64, long e) {
    if (f64) return (int)(((const long long*)ei)[e]);
    return ((const int*)ei)[e];
}
// wave-uniform broadcast of lane k's value (k must be compile-time constant)
__device__ __forceinline__ float bcast(float v, int k) {
    return __int_as_float(__builtin_amdgcn_readlane(__float_as_int(v), k));
}

// unpack 8 bf16 (uint4) and fma into acc[8] with scalar weight d
__device__ __forceinline__ void fma8(float* acc, uint4 v, float d) {
    acc[0] = fmaf(__uint_as_float(v.x << 16), d, acc[0]);
    acc[1] = fmaf(__uint_as_float(v.x & 0xffff0000u), d, acc[1]);
    acc[2] = fmaf(__uint_as_float(v.y << 16), d, acc[2]);
    acc[3] = fmaf(__uint_as_float(v.y & 0xffff0000u), d, acc[3]);
    acc[4] = fmaf(__uint_as_float(v.z << 16), d, acc[4]);
    acc[5] = fmaf(__uint_as_float(v.z & 0xffff0000u), d, acc[5]);
    acc[6] = fmaf(__uint_as_float(v.w << 16), d, acc[6]);
    acc[7] = fmaf(__uint_as_float(v.w & 0xffff0000u), d, acc[7]);
}

__global__ void stamp_kernel(float* out, int n, float v) {
    int i = blockIdx.x * blockDim.x + threadIdx.x;
    if (i < n) out[i] = v;
}

// flags[0]: edge int64?  flags[1+b]: per-float-input fp32?
// w=0..12: one wave per buffer; w=13: edge probe + zero gcnt;
// w=14/15: zero statsA/statsB (128 floats each).
__global__ void detect_all(const int* ei_raw,
                           const void* x, const void* W1, const void* b1,
                           const void* g1, const void* be1, const void* W2,
                           const void* b2, const void* g2, const void* be2,
                           const void* Wmu, const void* bmu, const void* Wls,
                           const void* bls, int* flags,
                           float* statsA, float* statsB, int* gcnt) {
    int w = threadIdx.x >> 6;
    int lane = threadIdx.x & 63;
    if (w == 14) {
        for (int i = lane; i < 128; i += 64) statsA[i] = 0.0f;
        return;
    }
    if (w == 15) {
        for (int i = lane; i < 128; i += 64) statsB[i] = 0.0f;
        return;
    }
    if (w == 13) {
        int acc = ei_raw[2 * lane * 11003 + 1] |
                  ei_raw[2 * (lane + 64) * 11003 + 1];
        unsigned long long b = __ballot(acc != 0);
        if (lane == 0) flags[0] = (b == 0ull) ? 1 : 0;
        for (int i = lane; i < NBUCKET; i += 64) gcnt[i] = 0;
        return;
    }
    const void* bufs[13] = { x, W1, b1, g1, be1, W2, b2, g2, be2, Wmu, bmu, Wls, bls };
    const int   ns[13]   = { 512, 512, 64, 64, 64, 512, 64, 64, 64, 512, 32, 512, 32 };
    const unsigned short* u = (const unsigned short*)bufs[w];
    int n = ns[w];
    int evenZero = 0;
    bool oddNz = false, anyNz = false, big = false;
    for (int i = lane; i < n; i += 64) {
        unsigned short s = u[i];
        if (s) anyNz = true;
        if (i & 1) { if (s) oddNz = true; }
        else {
            if ((s & 0x7F80u) == 0x7F80u) big = true;
            else if (fabsf(bfu2f(s)) > 100.0f) big = true;
            if (s == 0) evenZero++;
        }
    }
    unsigned long long anyB = __ballot(anyNz);
    unsigned long long oddB = __ballot(oddNz);
    unsigned long long bigB = __ballot(big);
#pragma unroll
    for (int o = 1; o < 64; o <<= 1) evenZero += __shfl_xor(evenZero, o);
    if (lane == 0) {
        int fp32 = 0;
        if (anyB != 0ull) {
            if (bigB != 0ull) fp32 = 1;
            else if (evenZero >= n / 4 && oddB != 0ull) fp32 = 1;
        }
        flags[1 + w] = fp32;
    }
}

__global__ void convert_weights(const void* W1, const void* W2,
                                const void* Wmu, const void* Wls,
                                const void* b1, const void* b2,
                                const void* bmu, const void* bls,
                                const int* flags,
                                float* W1f, float* W2f, float* Wcatf,
                                float* b1f, float* b2f, float* bcatf) {
    int i = blockIdx.x * blockDim.x + threadIdx.x;
    if (i < IN_DIM * HID) { W1f[i] = loadf(W1, i, flags[2]); return; }
    i -= IN_DIM * HID;
    if (i < HID * HID) { W2f[i] = loadf(W2, i, flags[6]); return; }
    i -= HID * HID;
    if (i < HID * HID) {
        int k = i >> 6;
        int j = i & 63;
        if (j < LAT) Wcatf[i] = loadf(Wmu, (size_t)k * LAT + j, flags[10]);
        else         Wcatf[i] = loadf(Wls, (size_t)k * LAT + (j - LAT), flags[12]);
        return;
    }
    i -= HID * HID;
    if (i < HID) { b1f[i] = loadf(b1, i, flags[3]); return; }
    i -= HID;
    if (i < HID) { b2f[i] = loadf(b2, i, flags[7]); return; }
    i -= HID;
    if (i < HID) {
        if (i < LAT) bcatf[i] = loadf(bmu, i, flags[11]);
        else         bcatf[i] = loadf(bls, i - LAT, flags[13]);
    }
}

// ---- single-pass bucketed scatter (fixed-capacity buckets) ----
// 1024 threads/block, EPB=8192: same per-block write granularity as the
// 69us round-9 version (~21 records/bucket/block) but 4x the waves.
__global__ void bucket_scatter(const void* ei, const int* flags, int* gcnt,
                               int* staged) {
    __shared__ int h[NBUCKET];
    __shared__ int lbase[NBUCKET];
    __shared__ int lcnt[NBUCKET];
    for (int i = threadIdx.x; i < NBUCKET; i += SCT) { h[i] = 0; lcnt[i] = 0; }
    __syncthreads();
    int f64 = flags[0];
    long e0 = (long)blockIdx.x * EPB;
    for (int i = 0; i < EPB / SCT; i++) {
        long e = e0 + i * SCT + threadIdx.x;
        if (e < N_EDGES) atomicAdd(&h[load_dst(ei, f64, e) >> 8], 1);
    }
    __syncthreads();
    for (int i = threadIdx.x; i < NBUCKET; i += SCT)
        lbase[i] = h[i] ? atomicAdd(&gcnt[i], h[i]) : 0;
    __syncthreads();
    for (int i = 0; i < EPB / SCT; i++) {
        long e = e0 + i * SCT + threadIdx.x;
        if (e < N_EDGES) {
            int d = load_dst(ei, f64, e);
            int s = load_src(ei, f64, e);
            int b = d >> 8;
            int off = atomicAdd(&lcnt[b], 1);
            staged[(b << 14) + lbase[b] + off] = ((d & 255) << 17) | s;
        }
    }
}

// one block (1024 threads) per bucket: prefix over gcnt, deg/scan, scatter.
// Edge loops use all 1024 threads; 256-wide scan phases guard with t<256.
__global__ void csr_build(const int* gcnt, const int* staged, float* dis,
                          int* row_start, int* csr) {
    int b = blockIdx.x;
    int t = threadIdx.x;
    int n0 = b << 8;
    int nn = N_NODES - n0;
    if (nn > 256) nn = 256;
    __shared__ int sd[256];
    __shared__ int ldeg[256];
    __shared__ int lcur[256];
    __shared__ int se0;
    if (t < 256) {
        int p = 0;
        for (int i = t; i < b; i += 256) p += gcnt[i];
        sd[t] = p;
    }
    __syncthreads();
    for (int off = 128; off >= 1; off >>= 1) {
        if (t < off) sd[t] += sd[t + off];
        __syncthreads();
    }
    if (t == 0) se0 = sd[0];
    if (t < 256) ldeg[t] = 0;
    __syncthreads();
    int e0 = se0;
    int cntb = gcnt[b];
    const int* sb = staged + ((size_t)b << 14);
    for (int i = t; i < cntb; i += 1024)
        atomicAdd(&ldeg[sb[i] >> 17], 1);
    __syncthreads();
    int v = 0;
    if (t < 256) { v = ldeg[t]; sd[t] = v; }
    __syncthreads();
    for (int off = 1; off < 256; off <<= 1) {
        int x = 0;
        if (t < 256 && t >= off) x = sd[t - off];
        __syncthreads();
        if (t < 256) sd[t] += x;
        __syncthreads();
    }
    if (t < 256) {
        int excl = sd[t] - v;
        if (t < nn) {
            dis[n0 + t] = rsqrtf((float)(v + 1));
            row_start[n0 + t] = e0 + excl;
        }
        lcur[t] = e0 + excl;
    }
    __syncthreads();
    for (int i = t; i < cntb; i += 1024) {
        int rec = sb[i];
        int pos = atomicAdd(&lcur[rec >> 17], 1);
        csr[pos] = rec & 0x1FFFF;
    }
    if (b == NBUCKET - 1 && t == 0) row_start[N_NODES] = e0 + cntb;
}

// ---- dense layers: one wave per 4 nodes, lane = output feature ----
__global__ void gemm_l1(const void* X, const int* flags, const float* W,
                        unsigned short* T) {
    int wid = (blockIdx.x * blockDim.x + threadIdx.x) >> 6;
    int n0 = wid * 4;
    if (n0 >= N_NODES) return;
    int lane = threadIdx.x & 63;
    int fp = flags[1];
    float xa[4], xb[4];
#pragma unroll
    for (int nn = 0; nn < 4; nn++) {
        size_t base = (size_t)(n0 + nn) * IN_DIM;
        xa[nn] = loadf(X, base + lane, fp);
        xb[nn] = (lane < IN_DIM - 64) ? loadf(X, base + 64 + lane, fp) : 0.0f;
    }
    float acc[4] = { 0.0f, 0.0f, 0.0f, 0.0f };
    const float* Wp = W + lane;
#pragma unroll
    for (int k = 0; k < 64; k++) {
        float w = Wp[k * HID];
#pragma unroll
        for (int nn = 0; nn < 4; nn++)
            acc[nn] = fmaf(bcast(xa[nn], k), w, acc[nn]);
    }
#pragma unroll
    for (int k = 0; k < IN_DIM - 64; k++) {
        float w = Wp[(64 + k) * HID];
#pragma unroll
        for (int nn = 0; nn < 4; nn++)
            acc[nn] = fmaf(bcast(xb[nn], k), w, acc[nn]);
    }
#pragma unroll
    for (int nn = 0; nn < 4; nn++)
        T[(size_t)(n0 + nn) * HID + lane] = f2bfu(acc[nn]);
}

// BN finalize inlined: lane reads stats[lane]/stats[64+lane] (L2-cached),
// computes scale/shift, then gemm.
__global__ void gemm_bn(const float* F, const float* W, const float* stats,
                        const void* gw, const void* bw, const int* flags,
                        int gf, int bf, unsigned short* T) {
    int wid = (blockIdx.x * blockDim.x + threadIdx.x) >> 6;
    int n0 = wid * 4;
    if (n0 >= N_NODES) return;
    int lane = threadIdx.x & 63;
    float s = stats[lane];
    float q = stats[64 + lane];
    const float inv_n = 1.0f / (float)N_NODES;
    float mean = s * inv_n;
    float var = q * inv_n - mean * mean;
    float sc = loadf(gw, lane, flags[gf]) * rsqrtf(var + BN_EPS);
    float sh = loadf(bw, lane, flags[bf]) - mean * sc;
    float a[4];
#pragma unroll
    for (int nn = 0; nn < 4; nn++) {
        float f = F[(size_t)(n0 + nn) * HID + lane];
        a[nn] = fmaxf(f * sc + sh, 0.0f);
    }
    float acc[4] = { 0.0f, 0.0f, 0.0f, 0.0f };
    const float* Wp = W + lane;
#pragma unroll
    for (int k = 0; k < HID; k++) {
        float w = Wp[k * HID];
#pragma unroll
        for (int nn = 0; nn < 4; nn++)
            acc[nn] = fmaf(bcast(a[nn], k), w, acc[nn]);
    }
#pragma unroll
    for (int nn = 0; nn < 4; nn++)
        T[(size_t)(n0 + nn) * HID + lane] = f2bfu(acc[nn]);
}

// ---- aggregation: one wave per node, lane = g*8+c, 4 chains ----
__global__ void agg_mid(const unsigned short* T, const int* row_start, const int* csr,
                        const float* dis, const float* bias, float* F) {
    int wid = (blockIdx.x * blockDim.x + threadIdx.x) >> 6;
    if (wid >= N_NODES) return;
    int lane = threadIdx.x & 63;
    int g = lane >> 3;
    int c = lane & 7;
    float dn = dis[wid];
    float acc[8];
#pragma unroll
    for (int k = 0; k < 8; k++) acc[k] = 0.0f;
    if (g == 0) {
        uint4 v = ((const uint4*)(T + (size_t)wid * HID))[c];
        fma8(acc, v, dn);
    }
    int s0 = row_start[wid];
    int s1 = row_start[wid + 1];
    for (int e = s0; e < s1; e += 32) {
        int i0 = e + g;
        int i1 = e + 8 + g;
        int i2 = e + 16 + g;
        int i3 = e + 24 + g;
        int m0 = i0 < s1, m1 = i1 < s1, m2 = i2 < s1, m3 = i3 < s1;
        int n0i = csr[m0 ? i0 : s0];
        int n1i = csr[m1 ? i1 : s0];
        int n2i = csr[m2 ? i2 : s0];
        int n3i = csr[m3 ? i3 : s0];
        float d0 = m0 ? dis[n0i] : 0.0f;
        float d1 = m1 ? dis[n1i] : 0.0f;
        float d2 = m2 ? dis[n2i] : 0.0f;
        float d3 = m3 ? dis[n3i] : 0.0f;
        uint4 v0 = ((const uint4*)(T + (size_t)n0i * HID))[c];
        uint4 v1 = ((const uint4*)(T + (size_t)n1i * HID))[c];
        uint4 v2 = ((const uint4*)(T + (size_t)n2i * HID))[c];
        uint4 v3 = ((const uint4*)(T + (size_t)n3i * HID))[c];
        fma8(acc, v0, d0);
        fma8(acc, v1, d1);
        fma8(acc, v2, d2);
        fma8(acc, v3, d3);
    }
#pragma unroll
    for (int k = 0; k < 8; k++) {
        float v = acc[k];
        v += __shfl_xor(v, 8);
        v += __shfl_xor(v, 16);
        v += __shfl_xor(v, 32);
        acc[k] = v;
    }
    if (g == 0) {
        const float4* bp = (const float4*)(bias + c * 8);
        float4 b0 = bp[0];
        float4 b1 = bp[1];
        float4 r0, r1;
        r0.x = b0.x + dn * acc[0];
        r0.y = b0.y + dn * acc[1];
        r0.z = b0.z + dn * acc[2];
        r0.w = b0.w + dn * acc[3];
        r1.x = b1.x + dn * acc[4];
        r1.y = b1.y + dn * acc[5];
        r1.z = b1.z + dn * acc[6];
        r1.w = b1.w + dn * acc[7];
        float4* o = (float4*)(F + (size_t)wid * HID + c * 8);
        o[0] = r0;
        o[1] = r1;
    }
}

__global__ void agg_out(const unsigned short* T, const int* row_start, const int* csr,
                        const float* dis, const float* bias, float* out) {
    int wid = (blockIdx.x * blockDim.x + threadIdx.x) >> 6;
    if (wid >= N_NODES) return;
    int lane = threadIdx.x & 63;
    int g = lane >> 3;
    int c = lane & 7;
    float dn = dis[wid];
    float acc[8];
#pragma unroll
    for (int k = 0; k < 8; k++) acc[k] = 0.0f;
    if (g == 0) {
        uint4 v = ((const uint4*)(T + (size_t)wid * HID))[c];
        fma8(acc, v, dn);
    }
    int s0 = row_start[wid];
    int s1 = row_start[wid + 1];
    for (int e = s0; e < s1; e += 32) {
        int i0 = e + g;
        int i1 = e + 8 + g;
        int i2 = e + 16 + g;
        int i3 = e + 24 + g;
        int m0 = i0 < s1, m1 = i1 < s1, m2 = i2 < s1, m3 = i3 < s1;
        int n0i = csr[m0 ? i0 : s0];
        int n1i = csr[m1 ? i1 : s0];
        int n2i = csr[m2 ? i2 : s0];
        int n3i = csr[m3 ? i3 : s0];
        float d0 = m0 ? dis[n0i] : 0.0f;
        float d1 = m1 ? dis[n1i] : 0.0f;
        float d2 = m2 ? dis[n2i] : 0.0f;
        float d3 = m3 ? dis[n3i] : 0.0f;
        uint4 v0 = ((const uint4*)(T + (size_t)n0i * HID))[c];
        uint4 v1 = ((const uint4*)(T + (size_t)n1i * HID))[c];
        uint4 v2 = ((const uint4*)(T + (size_t)n2i * HID))[c];
        uint4 v3 = ((const uint4*)(T + (size_t)n3i * HID))[c];
        fma8(acc, v0, d0);
        fma8(acc, v1, d1);
        fma8(acc, v2, d2);
        fma8(acc, v3, d3);
    }
#pragma unroll
    for (int k = 0; k < 8; k++) {
        float v = acc[k];
        v += __shfl_xor(v, 8);
        v += __shfl_xor(v, 16);
        v += __shfl_xor(v, 32);
        acc[k] = v;
    }
    if (g == 0) {
        const float4* bp = (const float4*)(bias + c * 8);
        float4 b0 = bp[0];
        float4 b1 = bp[1];
        float4 r0, r1;
        r0.x = b0.x + dn * acc[0];
        r0.y = b0.y + dn * acc[1];
        r0.z = b0.z + dn * acc[2];
        r0.w = b0.w + dn * acc[3];
        r1.x = b1.x + dn * acc[4];
        r1.y = b1.y + dn * acc[5];
        r1.z = b1.z + dn * acc[6];
        r1.w = b1.w + dn * acc[7];
        float4* o;
        if (c < 4)
            o = (float4*)(out + (size_t)wid * LAT + c * 8);
        else
            o = (float4*)(out + (size_t)N_NODES * LAT + (size_t)wid * LAT + (c - 4) * 8);
        o[0] = r0;
        o[1] = r1;
    }
}

__global__ void stats_kernel(const float* F, float* stats) {
    int lane = threadIdx.x & 63;
    float s = 0.0f;
    float q = 0.0f;
    int wv = threadIdx.x >> 6;
    for (int r = blockIdx.x * 4 + wv; r < N_NODES; r += gridDim.x * 4) {
        float v = F[(size_t)r * HID + lane];
        s += v;
        q += v * v;
    }
    __shared__ float ls[256];
    __shared__ float lq[256];
    ls[threadIdx.x] = s;
    lq[threadIdx.x] = q;
    __syncthreads();
    if (threadIdx.x < 64) {
        s = ls[threadIdx.x] + ls[64 + threadIdx.x] + ls[128 + threadIdx.x] + ls[192 + threadIdx.x];
        q = lq[threadIdx.x] + lq[64 + threadIdx.x] + lq[128 + threadIdx.x] + lq[192 + threadIdx.x];
        atomicAdd(&stats[lane], s);
        atomicAdd(&stats[64 + lane], q);
    }
}

extern "C" void kernel_launch(void* const* d_in, const int* in_sizes, int n_in,
                              void* d_out, int out_size, void* d_ws, size_t ws_size,
                              hipStream_t stream) {
    (void)in_sizes;
    (void)n_in;
    const void* x   = d_in[0];
    const void* ei  = d_in[1];
    const void* W1  = d_in[2];
    const void* b1  = d_in[3];
    const void* g1  = d_in[4];
    const void* be1 = d_in[5];
    const void* W2  = d_in[6];
    const void* b2  = d_in[7];
    const void* g2  = d_in[8];
    const void* be2 = d_in[9];
    const void* Wmu = d_in[10];
    const void* bmu = d_in[11];
    const void* Wls = d_in[12];
    const void* bls = d_in[13];
    float* out = (float*)d_out;

    char* base = (char*)d_ws;
    size_t off = 0;
    // staged (NBUCKET*BCAP ints) unioned with F (N_NODES*HID floats):
    // staged dead after csr_build; F first written by agg_mid (later).
    int*   staged = (int*)(base + off);
    float* F      = (float*)(base + off);
    size_t uni = (size_t)NBUCKET * BCAP * 4;
    if ((size_t)N_NODES * HID * 4 > uni) uni = (size_t)N_NODES * HID * 4;
    off += uni;                        off = (off + 511) & ~(size_t)511;
    int* csr = (int*)(base + off);
    off += (size_t)N_EDGES * 4;        off = (off + 511) & ~(size_t)511;
    unsigned short* T = (unsigned short*)(base + off);
    off += (size_t)N_NODES * HID * 2;  off = (off + 511) & ~(size_t)511;
    float* dis = (float*)(base + off);
    off += (size_t)N_NODES * 4;        off = (off + 511) & ~(size_t)511;
    int* row_start = (int*)(base + off);
    off += (size_t)(N_NODES + 1) * 4;  off = (off + 511) & ~(size_t)511;
    int* gcnt = (int*)(base + off);
    off += NBUCKET * 4;                off = (off + 511) & ~(size_t)511;
    int* flags = (int*)(base + off);
    off += 512;                        off = (off + 511) & ~(size_t)511;
    float* W1f = (float*)(base + off);
    off += (size_t)IN_DIM * HID * 4;   off = (off + 511) & ~(size_t)511;
    float* W2f = (float*)(base + off);
    off += (size_t)HID * HID * 4;      off = (off + 511) & ~(size_t)511;
    float* Wcatf = (float*)(base + off);
    off += (size_t)HID * HID * 4;      off = (off + 511) & ~(size_t)511;
    float* b1f = (float*)(base + off);
    off += HID * 4;                    off = (off + 511) & ~(size_t)511;
    float* b2f = (float*)(base + off);
    off += HID * 4;                    off = (off + 511) & ~(size_t)511;
    float* bcatf = (float*)(base + off);
    off += HID * 4;                    off = (off + 511) & ~(size_t)511;
    float* statsA = (float*)(base + off);
    off += 128 * 4;                    off = (off + 511) & ~(size_t)511;
    float* statsB = (float*)(base + off);
    off += 128 * 4;                    off = (off + 511) & ~(size_t)511;

    const int BT = 256;
    int gW   = (N_NODES * 64 + BT - 1) / BT;         // 25000 (wave per node)
    int gG   = ((N_NODES / 4) * 64 + BT - 1) / BT;   // 6250  (wave per 4 nodes)
    int gOut = (out_size + BT - 1) / BT;
    int gCv  = (IN_DIM * HID + 2 * HID * HID + 3 * HID + BT - 1) / BT;

    if (ws_size < off) {
        stamp_kernel<<<gOut, BT, 0, stream>>>(out, out_size, 6.8e37f);
        return;
    }

    detect_all<<<1, 1024, 0, stream>>>((const int*)ei, x, W1, b1, g1, be1, W2, b2,
                                       g2, be2, Wmu, bmu, Wls, bls, flags,
                                       statsA, statsB, gcnt);
    convert_weights<<<gCv, BT, 0, stream>>>(W1, W2, Wmu, Wls, b1, b2, bmu, bls,
                                            flags, W1f, W2f, Wcatf, b1f, b2f, bcatf);

    // CSR build: single-pass scatter into fixed-capacity buckets, then build
    bucket_scatter<<<NBLK_E, SCT, 0, stream>>>(ei, flags, gcnt, staged);
    csr_build<<<NBUCKET, 1024, 0, stream>>>(gcnt, staged, dis, row_start, csr);

    // layer 1
    gemm_l1<<<gG, BT, 0, stream>>>(x, flags, W1f, T);
    agg_mid<<<gW, BT, 0, stream>>>(T, row_start, csr, dis, b1f, F);
    stats_kernel<<<256, BT, 0, stream>>>(F, statsA);

    // layer 2 (BN1 finalize inlined)
    gemm_bn<<<gG, BT, 0, stream>>>(F, W2f, statsA, g1, be1, flags, 4, 5, T);
    agg_mid<<<gW, BT, 0, stream>>>(T, row_start, csr, dis, b2f, F);
    stats_kernel<<<256, BT, 0, stream>>>(F, statsB);

    // layer 3 (BN2 finalize inlined) -> output
    gemm_bn<<<gG, BT, 0, stream>>>(F, Wcatf, statsB, g2, be2, flags, 8, 9, T);
    agg_out<<<gW, BT, 0, stream>>>(T, row_start, csr, dis, bcatf, out);
}